// Round 3
// baseline (278.012 us; speedup 1.0000x reference)
//
#include <hip/hip_runtime.h>

// TAdaConv2d via bf16 MFMA implicit GEMM — fused, barrier-free, LDS-traffic-minimized.
//   out[b,co,t,y,w] = bias[co] + sum_{ci,ky,kx} x[b,ci,t,y+ky-1,w+kx-1]*alpha[b,ci,t]*W[co,ci,ky,kx]
//
// R3 change vs R2 (conv4, 112 us): conv4's wave=(q,ph) made every B-fragment be read by
// 4 waves -> 1.18 MB LDS reads/block (LDS-BW floor ~46 us/CU). Governing metric is LDS
// bytes/MFMA. conv5: wave = (mg co-HALF in regs, row) x Nw=4 pixel-tiles:
//   - 144 VGPRs of weights (2 quarters), each B-read feeds 2 MFMAs -> 0.5 KB/MFMA,
//     2x less LDS traffic than conv4 (~23 us/CU floor).
//   - 256-thread 2-row blocks, ~200 VGPR -> 2 waves/SIMD AND 2 blocks/CU: staging of one
//     block overlaps MFMA stream of the other (conv3/4 had no such overlap).
//   - still exactly ONE __syncthreads; A never touches LDS; xs read-only after staging.
// Accumulation order (tap,kc) unchanged -> bit-identical, absmax 0.0156.

#define CIN  64
#define COUT 64
#define TT   16
#define BB   8
#define HH   64
#define WW   64

typedef __attribute__((ext_vector_type(8))) short bf16x8;
typedef __attribute__((ext_vector_type(4))) float f32x4;

__device__ __forceinline__ unsigned short f2bf(float f) {
    // round-to-nearest-even fp32 -> bf16
    union { float f; unsigned u; } v; v.f = f;
    unsigned r = (v.u + 0x7FFF + ((v.u >> 16) & 1)) >> 16;
    return (unsigned short)r;
}

// ---------------- prep_w: weight -> wb[q][tap][kc][kg][co_l][8] bf16 ----------------
// Fragment-direct: lane (kg*16+co_l) of quarter q reads A for (tap,kc) as one b128:
// co = q*16+co_l, ci = kc*32 + kg*8 + e.
__global__ __launch_bounds__(256) void prep_w(const float* __restrict__ wgt,
                                              unsigned short* __restrict__ wb) {
    int idx = blockIdx.x * 256 + threadIdx.x;   // over co*ci*tap = 36864
    if (idx < COUT * CIN * 9) {
        int co  = idx / (CIN * 9);
        int r   = idx - co * (CIN * 9);
        int ci  = r / 9;
        int tap = r - ci * 9;
        int q    = co >> 4;
        int co_l = co & 15;
        int kc   = ci >> 5;
        int kg   = (ci >> 3) & 3;
        int e    = ci & 7;
        wb[(((((q * 9 + tap) * 2 + kc) * 4 + kg) * 16) + co_l) * 8 + e] = f2bf(wgt[idx]);
    }
}

// ---------------- conv5: fused stage + register-weight MFMA, Mw=2 x Nw=4 ----------------
// block: (bt, ytile): 2 output rows x 64 w, all 64 co. 4 waves = (mg co-half) x (rw row).
// Each wave: 32 co x 1 row x 64 w; B-fragment read once, used by both co-quarters.
__global__ __launch_bounds__(256, 2) void conv5(const float* __restrict__ x,
                                                const float* __restrict__ alpha,
                                                const short* __restrict__ wb,
                                                const float* __restrict__ bias,
                                                float* __restrict__ out) {
    __shared__ __align__(16) short xs[4 * 4224];   // 4 rows x (66 px x 64 ci) bf16, 33.8 KB

    // XCD-aware bijective swizzle: 4096 blocks, 8 XCDs -> 512 consecutive blk per XCD
    // = 16 full (b,t) planes incl. all ytiles (halo rows L2-hit).
    const int orig  = blockIdx.x;
    const int blk   = (orig & 7) * 512 + (orig >> 3);
    const int ytile = blk & 31;
    const int bt    = blk >> 5;
    const int t     = bt & 15;
    const int b     = bt >> 4;
    const int y0    = ytile * 2;
    const int tid   = threadIdx.x;
    const int wv    = tid >> 6;
    const int lane  = tid & 63;
    const int co_l  = lane & 15;
    const int kg    = lane >> 4;
    const int mg    = wv >> 1;           // co half (0/1): quarters 2mg, 2mg+1
    const int rw    = wv & 1;            // output row within tile

    // ---- weight fragments -> 144 VGPRs (issued first; latency hides under staging) ----
    bf16x8 wreg[2][9][2];
#pragma unroll
    for (int m = 0; m < 2; ++m)
#pragma unroll
        for (int tap = 0; tap < 9; ++tap)
#pragma unroll
            for (int kc = 0; kc < 2; ++kc)
                wreg[m][tap][kc] = *(const bf16x8*)(
                    wb + ((((mg * 2 + m) * 9 + tap) * 2 + kc) * 64 + lane) * 8);

    // ---- fused x staging: wave wv owns ci range [wv*16, wv*16+16) for all 4 rows ----
    {
        const int ci0 = wv * 16;
        // halo columns px=-1 and px=64: wave wv zeroes row wv's 2x8 slots
        if (lane < 16) {
            int4 z = {0, 0, 0, 0};
            *(int4*)(xs + wv * 4224 + (lane >> 3) * 4160 + (lane & 7) * 8) = z;
        }
#pragma unroll
        for (int r = 0; r < 4; ++r) {
            const int gy = y0 - 1 + r;
            short* rowb = xs + r * 4224;
#pragma unroll
            for (int gi = 0; gi < 2; ++gi) {
                const int g  = wv * 2 + gi;       // ci group of 8
                const int cg = ci0 + gi * 8;
                int4 o = {0, 0, 0, 0};
                if ((unsigned)gy < HH) {
                    const float* p = x + ((size_t)((b * CIN + cg) * TT + t) * HH + gy) * WW + lane;
                    float v0 = p[0 * 65536] * alpha[(b * CIN + cg + 0) * TT + t];
                    float v1 = p[1 * 65536] * alpha[(b * CIN + cg + 1) * TT + t];
                    float v2 = p[2 * 65536] * alpha[(b * CIN + cg + 2) * TT + t];
                    float v3 = p[3 * 65536] * alpha[(b * CIN + cg + 3) * TT + t];
                    float v4 = p[4 * 65536] * alpha[(b * CIN + cg + 4) * TT + t];
                    float v5 = p[5 * 65536] * alpha[(b * CIN + cg + 5) * TT + t];
                    float v6 = p[6 * 65536] * alpha[(b * CIN + cg + 6) * TT + t];
                    float v7 = p[7 * 65536] * alpha[(b * CIN + cg + 7) * TT + t];
                    o.x = (int)f2bf(v0) | ((int)f2bf(v1) << 16);
                    o.y = (int)f2bf(v2) | ((int)f2bf(v3) << 16);
                    o.z = (int)f2bf(v4) | ((int)f2bf(v5) << 16);
                    o.w = (int)f2bf(v6) | ((int)f2bf(v7) << 16);
                }
                *(int4*)(rowb + (lane + 1) * 64 + ((g ^ (lane & 7)) * 8)) = o;
            }
        }
    }
    __syncthreads();   // the ONLY barrier

    // ---- barrier-free MFMA main loop: 72 ds_read_b128, 144 MFMA per wave ----
    f32x4 acc[2][4] = {};     // [m quarter][n tile]
    int si[3][2];             // per-(dx,kc) base index; n folds into +n*1024 offset imm
#pragma unroll
    for (int dxi = 0; dxi < 3; ++dxi)
#pragma unroll
        for (int kc = 0; kc < 2; ++kc) {
            int wx = co_l + dxi - 1;                       // -1..15
            si[dxi][kc] = (wx + 1) * 64 + (((kc * 4 + kg) ^ (wx & 7)) * 8);
        }

#pragma unroll
    for (int tap = 0; tap < 9; ++tap) {
        const int ky  = tap / 3;
        const int dxi = tap - 3 * ky;
        const short* rowp = xs + (rw + ky) * 4224;         // input row y0+rw+ky-1
#pragma unroll
        for (int kc = 0; kc < 2; ++kc) {
            const short* bp = rowp + si[dxi][kc];
#pragma unroll
            for (int n = 0; n < 4; ++n) {
                bf16x8 bfr = *(const bf16x8*)(bp + n * 1024);   // offset imm
                acc[0][n] = __builtin_amdgcn_mfma_f32_16x16x32_bf16(
                    wreg[0][tap][kc], bfr, acc[0][n], 0, 0, 0);
                acc[1][n] = __builtin_amdgcn_mfma_f32_16x16x32_bf16(
                    wreg[1][tap][kc], bfr, acc[1][n], 0, 0, 0);
            }
        }
    }

    // ---- epilogue ----
    const int y = y0 + rw;
#pragma unroll
    for (int m = 0; m < 2; ++m) {
#pragma unroll
        for (int rr = 0; rr < 4; ++rr) {
            const int co = (mg * 2 + m) * 16 + kg * 4 + rr;
            const float bv = bias[co];
            float* op = out + (size_t)(((b * COUT + co) * TT + t) * HH + y) * WW;
#pragma unroll
            for (int n = 0; n < 4; ++n)
                op[n * 16 + co_l] = acc[m][n][rr] + bv;
        }
    }
}

extern "C" void kernel_launch(void* const* d_in, const int* in_sizes, int n_in,
                              void* d_out, int out_size, void* d_ws, size_t ws_size,
                              hipStream_t stream) {
    const float* x      = (const float*)d_in[0];
    const float* alpha  = (const float*)d_in[1];
    const float* weight = (const float*)d_in[2];
    const float* bias   = (const float*)d_in[3];
    float* out          = (float*)d_out;

    // workspace: wb only (73.7 KB)
    unsigned short* wb = (unsigned short*)d_ws;

    hipLaunchKernelGGL(prep_w, dim3(144), dim3(256), 0, stream, weight, wb);
    hipLaunchKernelGGL(conv5, dim3(BB * TT * (HH / 2)), dim3(256), 0, stream,
                       x, alpha, (const short*)wb, bias, out);
}

// Round 4
// 269.059 us; speedup vs baseline: 1.0333x; 1.0333x over previous
//
#include <hip/hip_runtime.h>

// TAdaConv2d via bf16 MFMA implicit GEMM — persistent blocks + rolling LDS ring.
//   out[b,co,t,y,w] = bias[co] + sum_{ci,ky,kx} x[b,ci,t,y+ky-1,w+kx-1]*alpha[b,ci,t]*W[co,ci,ky,kx]
//
// R4 change vs R3 (conv5, 114 us, MfmaUtil 13%, Occupancy 20%): all three prior versions
// were latency-bound — 4096 short-lived blocks each paying full staging latency (scattered
// global loads + f2bf + barrier) before one 144-MFMA burst, at only ~2 waves/SIMD.
// conv6: 512 persistent blocks (= exactly 2/CU), each owning (b,t,y-quarter) = 16 output
// rows = 8 steps of 2 rows, with an 8-slot rolling ring of staged rows in LDS:
//   per step: [issue next-2-rows global loads] -> [144 MFMA, setprio(1)] -> [stores]
//             -> [vmcnt wait: convert+LDS-write] -> [one barrier]
// Staging latency hides under MFMA (T14); halo amp 2.0x -> 1.125x; prologue once per
// 16 rows. Wave map (mg co-half in 144 reg x rw row), swizzle, and (tap,kc) accumulation
// order identical to conv5 -> bit-identical numerics.

#define CIN  64
#define COUT 64
#define TT   16
#define BB   8
#define HH   64
#define WW   64
#define NSTEP 8

typedef __attribute__((ext_vector_type(8))) short bf16x8;
typedef __attribute__((ext_vector_type(4))) float f32x4;

__device__ __forceinline__ unsigned short f2bf(float f) {
    // round-to-nearest-even fp32 -> bf16
    union { float f; unsigned u; } v; v.f = f;
    unsigned r = (v.u + 0x7FFF + ((v.u >> 16) & 1)) >> 16;
    return (unsigned short)r;
}

// ---------------- prep_w: weight -> wb[q][tap][kc][kg][co_l][8] bf16 ----------------
__global__ __launch_bounds__(256) void prep_w(const float* __restrict__ wgt,
                                              unsigned short* __restrict__ wb) {
    int idx = blockIdx.x * 256 + threadIdx.x;   // over co*ci*tap = 36864
    if (idx < COUT * CIN * 9) {
        int co  = idx / (CIN * 9);
        int r   = idx - co * (CIN * 9);
        int ci  = r / 9;
        int tap = r - ci * 9;
        int q    = co >> 4;
        int co_l = co & 15;
        int kc   = ci >> 5;
        int kg   = (ci >> 3) & 3;
        int e    = ci & 7;
        wb[(((((q * 9 + tap) * 2 + kc) * 4 + kg) * 16) + co_l) * 8 + e] = f2bf(wgt[idx]);
    }
}

// ---------------- conv6: persistent-block rolling-ring MFMA implicit GEMM ----------------
// block: (bt, y-quarter): 16 output rows x 64 w, all 64 co; 8 steps of 2 rows.
// 4 waves = (mg co-half) x (rw row). xs = 8-slot ring of input rows.
__global__ __launch_bounds__(256, 2) void conv6(const float* __restrict__ x,
                                                const float* __restrict__ alpha,
                                                const short* __restrict__ wb,
                                                const float* __restrict__ bias,
                                                float* __restrict__ out) {
    __shared__ __align__(16) short xs[8 * 4224];   // 8 row slots x (66 px x 64 ci) bf16, 66 KB

    // XCD swizzle: 512 blocks = 8 XCDs x 64; all 4 quarters of a (b,t) on one XCD.
    const int orig = blockIdx.x;
    const int blk  = (orig & 7) * 64 + (orig >> 3);
    const int qy   = blk & 3;
    const int bt   = blk >> 2;
    const int t    = bt & 15;
    const int b    = bt >> 4;
    const int yb   = qy * 16;
    const int tid  = threadIdx.x;
    const int wv   = tid >> 6;
    const int lane = tid & 63;
    const int co_l = lane & 15;
    const int kg   = lane >> 4;
    const int mg   = wv >> 1;            // co half (quarters 2mg, 2mg+1) in registers
    const int rw   = wv & 1;             // output row within step

    // ---- weight fragments -> 144 VGPRs ----
    bf16x8 wreg[2][9][2];
#pragma unroll
    for (int m = 0; m < 2; ++m)
#pragma unroll
        for (int tap = 0; tap < 9; ++tap)
#pragma unroll
            for (int kc = 0; kc < 2; ++kc)
                wreg[m][tap][kc] = *(const bf16x8*)(
                    wb + ((((mg * 2 + m) * 9 + tap) * 2 + kc) * 64 + lane) * 8);

    // ---- alpha for this wave's two ci-groups (wave-uniform -> SGPR) ----
    float av[2][8];
#pragma unroll
    for (int gi = 0; gi < 2; ++gi)
#pragma unroll
        for (int j = 0; j < 8; ++j) {
            float a = alpha[(b * CIN + (wv + gi * 4) * 8 + j) * TT + t];
            av[gi][j] = __builtin_bit_cast(
                float, __builtin_amdgcn_readfirstlane(__builtin_bit_cast(int, a)));
        }

    const float* xbase0 = x + (size_t)((b * CIN + wv * 8) * TT + t) * (HH * WW);
    const float* xbase1 = x + (size_t)((b * CIN + (wv + 4) * 8) * TT + t) * (HH * WW);

    // ---- halo columns px=0, px=65 of all 8 slots: zero once ----
    if (tid < 128) {
        int slot = tid >> 4, col = (tid >> 3) & 1, sg = tid & 7;
        int4 z = {0, 0, 0, 0};
        *(int4*)(xs + slot * 4224 + col * 4160 + sg * 8) = z;
    }

    // ---- staging helpers (wave wv owns ci-groups {wv, wv+4} for both rows of a batch) ----
    float fb[2][2][8];                    // [row][gi][j] in-flight registers
    auto stage_load = [&](int gy0) {
#pragma unroll
        for (int r = 0; r < 2; ++r) {
            const int gy = gy0 + r;
            const bool ok = (unsigned)gy < HH;
            const float* p0 = xbase0 + gy * WW + lane;
            const float* p1 = xbase1 + gy * WW + lane;
#pragma unroll
            for (int j = 0; j < 8; ++j) {
                fb[r][0][j] = ok ? p0[j * 65536] : 0.0f;
                fb[r][1][j] = ok ? p1[j * 65536] : 0.0f;
            }
        }
    };
    auto stage_store = [&](int s0) {
#pragma unroll
        for (int r = 0; r < 2; ++r)
#pragma unroll
            for (int gi = 0; gi < 2; ++gi) {
                const int g = wv + gi * 4;
                int4 o;
                o.x = (int)f2bf(fb[r][gi][0] * av[gi][0]) | ((int)f2bf(fb[r][gi][1] * av[gi][1]) << 16);
                o.y = (int)f2bf(fb[r][gi][2] * av[gi][2]) | ((int)f2bf(fb[r][gi][3] * av[gi][3]) << 16);
                o.z = (int)f2bf(fb[r][gi][4] * av[gi][4]) | ((int)f2bf(fb[r][gi][5] * av[gi][5]) << 16);
                o.w = (int)f2bf(fb[r][gi][6] * av[gi][6]) | ((int)f2bf(fb[r][gi][7] * av[gi][7]) << 16);
                *(int4*)(xs + ((s0 + r) & 7) * 4224 + (lane + 1) * 64 + ((g ^ (lane & 7)) * 8)) = o;
            }
    };

    // ---- prologue: rows yb-1..yb+2 -> slots 0..3 ----
    stage_load(yb - 1); stage_store(0);
    stage_load(yb + 1); stage_store(2);

    int si[3][2];   // per-(dx,kc) ds base; pixel-tile n folds into +n*1024 offset imm
#pragma unroll
    for (int dxi = 0; dxi < 3; ++dxi)
#pragma unroll
        for (int kc = 0; kc < 2; ++kc) {
            int wx = co_l + dxi - 1;                       // -1..15
            si[dxi][kc] = (wx + 1) * 64 + (((kc * 4 + kg) ^ (wx & 7)) * 8);
        }

    __syncthreads();

    // ---- 8-step pipelined main loop ----
    for (int it = 0; it < NSTEP; ++it) {
        // (a) issue next-2-rows loads; latency hides under MFMA
        if (it < NSTEP - 1) stage_load(yb + 2 * it + 3);

        // (b) compute this step's 2 output rows
        f32x4 acc[2][4] = {};
        __builtin_amdgcn_s_setprio(1);
#pragma unroll
        for (int tap = 0; tap < 9; ++tap) {
            const int ky  = tap / 3;
            const int dxi = tap - 3 * ky;
            const short* rowp = xs + ((2 * it + rw + ky) & 7) * 4224;
#pragma unroll
            for (int kc = 0; kc < 2; ++kc) {
                const short* bp = rowp + si[dxi][kc];
#pragma unroll
                for (int n = 0; n < 4; ++n) {
                    bf16x8 bfr = *(const bf16x8*)(bp + n * 1024);   // offset imm
                    acc[0][n] = __builtin_amdgcn_mfma_f32_16x16x32_bf16(
                        wreg[0][tap][kc], bfr, acc[0][n], 0, 0, 0);
                    acc[1][n] = __builtin_amdgcn_mfma_f32_16x16x32_bf16(
                        wreg[1][tap][kc], bfr, acc[1][n], 0, 0, 0);
                }
            }
        }
        __builtin_amdgcn_s_setprio(0);

        // (c) epilogue stores (no dependence on (a))
        const int y = yb + 2 * it + rw;
#pragma unroll
        for (int m = 0; m < 2; ++m)
#pragma unroll
            for (int rr = 0; rr < 4; ++rr) {
                const int co = (mg * 2 + m) * 16 + kg * 4 + rr;
                const float bv = bias[co];
                float* op = out + (size_t)(((b * COUT + co) * TT + t) * HH + y) * WW;
#pragma unroll
                for (int n = 0; n < 4; ++n)
                    op[n * 16 + co_l] = acc[m][n][rr] + bv;
            }

        // (d) convert + ring write (vmcnt wait lands here), (e) barrier
        if (it < NSTEP - 1) stage_store(2 * it + 4);
        __syncthreads();
    }
}

extern "C" void kernel_launch(void* const* d_in, const int* in_sizes, int n_in,
                              void* d_out, int out_size, void* d_ws, size_t ws_size,
                              hipStream_t stream) {
    const float* x      = (const float*)d_in[0];
    const float* alpha  = (const float*)d_in[1];
    const float* weight = (const float*)d_in[2];
    const float* bias   = (const float*)d_in[3];
    float* out          = (float*)d_out;

    // workspace: wb only (73.7 KB)
    unsigned short* wb = (unsigned short*)d_ws;

    hipLaunchKernelGGL(prep_w, dim3(144), dim3(256), 0, stream, weight, wb);
    hipLaunchKernelGGL(conv6, dim3(8 * 64), dim3(256), 0, stream,
                       x, alpha, (const short*)wb, bias, out);
}